// Round 13
// baseline (185.525 us; speedup 1.0000x reference)
//
#include <hip/hip_runtime.h>
#include <math.h>

#define GG 15
#define KK 2048
#define NB 480               // co-resident: launch_bounds(256,2) -> 512 slots >= 480
#define N1F 983040.0f
#define EPS 1e-5f
#define PZN ((int)0xAAAAAAAA)   // harness poison pattern as int

typedef _Float16 half8 __attribute__((ext_vector_type(8)));
typedef float f32x4 __attribute__((ext_vector_type(4)));

// ---- ws float offsets ----
// R13 = R12 resubmitted verbatim (R12 died with a pytest core dump, no
// kernel-attributable signal; R7 precedent was infra). Structure: R11 +
// bid0-folded FINALS for every barrier. R8-R11 evidence: all sync protocols
// converge at ~12us/barrier; the common hidden cost is the consumer-side
// redundant stat reduce (480 blocks x 128 thr x 64 agent-scope aloads of
// the SAME 1-2KB region = ~4M requests to ~32 lines per phase). Fix: bid0's
// fold computes final BN coefs into COEF2..COEF5 / pre-divided FSREL;
// consumers do 2 aloads. Same math, computed once instead of 480x.
#define CENT  0        // [480][4]   exch: centroid
#define GSREL 1920     // [30][8]    add chain-16: centered moments
#define GBN1  2160     // [32][128]  add chain-15 (per batch): S[64]|Q[64]
#define SELO  6256     // [480][64]  exch: (g01>=0 ? max : min) extremum
#define FBN1  36976    // [128]      exch by bid0 fold of b1
#define H2A   37104    // [480][128] exch: h2a
#define H2B   98544    // [480][128] exch: h2b
#define H3A   159984   // [160][256] exch: h3a
#define H3B   200944   // [160][256] exch: h3b
#define GS2A  241904   // [2][256]   add chain-16: S[128]|Q[128]
#define GS2B  242416   // [2][256]
#define GS3A  242928   // [2][512]   S[256]|Q[256]
#define GS3B  243952   // [2][512] -> 244976
#define FSRELF 244976  // [8]    b0 fold: moments / N1F
#define COEF2 244984   // [256]  b2 fold: s2[128]|t2[128]
#define COEF3 245240   // [256]  b3 fold
#define COEF4 245496   // [512]  b4 fold: s4[256]|t4[256]
#define COEF5 246008   // [512]  b5 fold -> 246520
// int offsets (every slot/flag on its own 64B line)
#define CFLG  246528   // [6][30][16]  per-group done flags
#define ARRB  249408   // [6][480][16] per-block arrival slots (exch 1)

#define SMEMF 7936

__device__ const int SIDX[15] = {0,1,8, 2,4,6, 3,5,7, 9,11,13, 10,12,14};

__device__ __forceinline__ float wave_sum(float v){
    for (int off = 32; off; off >>= 1) v += __shfl_down(v, off, 64);
    return v;
}
__device__ __forceinline__ float aloadf(const float* p){
    return __hip_atomic_load(p, __ATOMIC_RELAXED, __HIP_MEMORY_SCOPE_AGENT);
}
__device__ __forceinline__ int aloadi(const int* p){
    return __hip_atomic_load(p, __ATOMIC_RELAXED, __HIP_MEMORY_SCOPE_AGENT);
}
// store-arrival barrier: depth-1 arrival (own slot), bid0 parallel-sweep
// detect + fold + 30 group-flag broadcast; others poll own group flag.
template<int SLP, class Fold>
__device__ __forceinline__ void sbar(int* wsi, int idx, int gi, int bid,
                                     int* sflag, Fold fold){
    __syncthreads();                    // drains this block's VMEM writes
    if (threadIdx.x == 0)
        atomicExch(&wsi[ARRB + (idx*480 + bid)*16], 1);
    if (bid == 0) {
        int guard = 0, done = 0;
        do {
            int ok = 1;
            for (int s = threadIdx.x; s < 480; s += 256)
                ok &= (aloadi(&wsi[ARRB + (idx*480 + s)*16]) == 1) ? 1 : 0;
            ok = __all(ok) ? 1 : 0;     // 64-lane AND
            if ((threadIdx.x & 63) == 0) sflag[2 + (threadIdx.x >> 6)] = ok;
            __syncthreads();
            done = sflag[2] & sflag[3] & sflag[4] & sflag[5];
            __syncthreads();            // protect sflag reuse next sweep
            if (!done) __builtin_amdgcn_s_sleep(SLP);
        } while (!done && ++guard < 4000000);
        fold();                         // all 480 arrived; data visible
        __syncthreads();                // drain fold exchs (vmcnt 0)
        if (threadIdx.x < 30)
            atomicExch(&wsi[CFLG + (idx*30 + threadIdx.x)*16], 1);
    }
    if (threadIdx.x == 0) {
        int g = 0;
        while (aloadi(&wsi[CFLG + (idx*30 + gi)*16]) != 1 && ++g < 8000000)
            __builtin_amdgcn_s_sleep(SLP);
    }
    __syncthreads();
    asm volatile("" ::: "memory");
}

__global__ void __launch_bounds__(256, 2) mega(
        const float* __restrict__ x,
        const float* __restrict__ w00, const float* __restrict__ g00, const float* __restrict__ b00,
        const float* __restrict__ w01, const float* __restrict__ g01, const float* __restrict__ b01,
        const float* __restrict__ w10, const float* __restrict__ g10, const float* __restrict__ b10,
        const float* __restrict__ w11, const float* __restrict__ g11, const float* __restrict__ b11,
        const float* __restrict__ w20, const float* __restrict__ g20, const float* __restrict__ b20,
        const float* __restrict__ w21, const float* __restrict__ g21, const float* __restrict__ b21,
        float* __restrict__ ws, float* __restrict__ out) {
    __shared__ __align__(16) float smemf[SMEMF];
    float* xls  = smemf;                       // [6144] phases 1-2 only
    float* redM = smemf + 6144; float* redN = smemf + 6400;
    float* redS = smemf + 6656; float* redQ = smemf + 6912;
    float* bcast= smemf + 7168;
    int*   sflag= (int*)(smemf + 7916);        // [6] ints
    // tail aliases (within xls 0..6143, dead after phase 2) -- conflict-free
    // strides (R9): f2b 69, vls 129, u3b 257.
    float* s1ls  = smemf;                      // [64]
    float* t1ls  = smemf + 64;                 // [64]
    float* centb = smemf + 128;                // [45]
    float* c2b   = smemf + 176;                // [15]
    float* c3b   = smemf + 192;                // [3]
    float* f2b   = smemf + 256;                // [15][69] -> 1291
    float* vls   = smemf + 1424;               // [15][129] -> 3359
    float* f3b   = smemf + 3360;               // [5][132] -> 4020
    float* u3b   = smemf + 4020;               // [5][257] -> 5305
    float* c2s   = smemf + 5312;               // [128]
    float* c2t   = smemf + 5440;               // [128]
    float* s4ls  = smemf + 5568;               // [256]
    float* t4ls  = smemf + 5824;               // [256] -> 6080
    float* hst   = smemf + 6912;               // [135] (redQ region, tail-safe)
    int* wsi = (int*)ws;

    int bid = blockIdx.x, tid = threadIdx.x;
    int b_ = bid / GG, g_ = bid % GG;
    int wv = tid >> 6, lane = tid & 63, l15 = lane & 15, quad = lane >> 4;
    int gi = bid >> 4;                 // 30 groups of 16 (flag polling groups)
    int sgrp = b_ >> 4;                // stats half-group (0/1)
    int base2 = g_*9,  nr2 = (g_ == 14) ? 2 : 9;    // L2 row chunk (128 rows)
    int base3 = g_*18, nr3 = (g_ == 14) ? 4 : 18;   // L3 row chunk (256 rows)

    // ================= phase 1: x -> LDS; centroid + 3x3 moments ===============
    {
        const float4* xp4 = (const float4*)(x + (size_t)bid * KK * 3);
        float4* xls4 = (float4*)xls;
        #pragma unroll
        for (int i = 0; i < 6; i++) xls4[i*256 + tid] = xp4[i*256 + tid];
        __syncthreads();
        float m[9] = {0,0,0,0,0,0,0,0,0};
        float a[24];
        const float* bp = &xls[tid*24];
        #pragma unroll
        for (int i = 0; i < 6; i++)
            *reinterpret_cast<float4*>(&a[i*4]) = *reinterpret_cast<const float4*>(&bp[i*4]);
        #pragma unroll
        for (int p = 0; p < 8; p++) {
            float ax=a[p*3], ay=a[p*3+1], az=a[p*3+2];
            m[0]+=ax; m[1]+=ay; m[2]+=az;
            m[3]=fmaf(ax,ax,m[3]); m[4]=fmaf(ay,ay,m[4]); m[5]=fmaf(az,az,m[5]);
            m[6]=fmaf(ax,ay,m[6]); m[7]=fmaf(ax,az,m[7]); m[8]=fmaf(ay,az,m[8]);
        }
        #pragma unroll
        for (int q = 0; q < 9; q++) {
            float v = wave_sum(m[q]);
            if (lane == 0) redM[q*4 + wv] = v;
        }
        __syncthreads();
        if (tid == 0) {
            float t[9];
            #pragma unroll
            for (int q = 0; q < 9; q++) t[q] = redM[q*4]+redM[q*4+1]+redM[q*4+2]+redM[q*4+3];
            float c0 = t[0]/KK, c1 = t[1]/KK, c2 = t[2]/KK;
            bcast[0]=c0; bcast[1]=c1; bcast[2]=c2;
            out[8192 + b_*(67*GG) + 0*GG + g_] = c0;
            out[8192 + b_*(67*GG) + 1*GG + g_] = c1;
            out[8192 + b_*(67*GG) + 2*GG + g_] = c2;
            atomicExch(&ws[CENT + bid*4 + 0], c0);
            atomicExch(&ws[CENT + bid*4 + 1], c1);
            atomicExch(&ws[CENT + bid*4 + 2], c2);
            redM[40] = t[3] - KK*c0*c0;  redM[41] = t[4] - KK*c1*c1;
            redM[42] = t[5] - KK*c2*c2;  redM[43] = t[6] - KK*c0*c1;
            redM[44] = t[7] - KK*c0*c2;  redM[45] = t[8] - KK*c1*c2;
        }
        __syncthreads();
    }
    if (tid < 6) atomicAdd(&ws[GSREL + gi*8 + tid], redM[40 + tid]);   // chain 16

    // hoisted A-frag prefetch (independent of barrier-0 data; completes in wait)
    half8 afA[4], afB[4];
    #pragma unroll
    for (int t = 0; t < 4; t++)
        #pragma unroll
        for (int j = 0; j < 8; j++) {
            afA[t][j] = (_Float16)w01[(t*16 + l15)*64 + quad*8 + j];
            afB[t][j] = (_Float16)w01[(t*16 + l15)*64 + 32 + quad*8 + j];
        }

    sbar<1>(wsi, 0, gi, bid, sflag, [&]{         // ---- b0 + SREL fold ----
        if (tid < 6) {
            float acc = 0.f;
            #pragma unroll
            for (int s = 0; s < 30; s++) acc += aloadf(&ws[GSREL + s*8 + tid]);
            atomicExch(&ws[FSRELF + tid], acc / N1F);
        }
    });

    if (tid < 6) bcast[3+tid] = aloadf(&ws[FSRELF + tid]);   // 2 aloads/block
    __syncthreads();
    float c0 = bcast[0], c1 = bcast[1], c2v = bcast[2];
    float S00=bcast[3], S11=bcast[4], S22=bcast[5], S01=bcast[6], S02=bcast[7], S12=bcast[8];

    // ================= phase 2: barrier-free MFMA over 2048 k ==================
    float wa0[8], wa1[8], wa2[8], ba[8], wb0[8], wb1[8], wb2[8], bb[8];
    #pragma unroll
    for (int j = 0; j < 8; j++) {
        int cA = quad*8 + j;
        float u0=w00[cA*3+0], u1=w00[cA*3+1], u2=w00[cA*3+2];
        float var = u0*u0*S00 + u1*u1*S11 + u2*u2*S22
                  + 2.f*(u0*u1*S01 + u0*u2*S02 + u1*u2*S12);
        float a1 = g00[cA]*rsqrtf(var + EPS);
        wa0[j]=a1*u0; wa1[j]=a1*u1; wa2[j]=a1*u2; ba[j]=b00[cA];
        int cB = cA + 32;
        float v0=w00[cB*3+0], v1=w00[cB*3+1], v2=w00[cB*3+2];
        float varB = v0*v0*S00 + v1*v1*S11 + v2*v2*S22
                   + 2.f*(v0*v1*S01 + v0*v2*S02 + v1*v2*S12);
        float a1B = g00[cB]*rsqrtf(varB + EPS);
        wb0[j]=a1B*v0; wb1[j]=a1B*v1; wb2[j]=a1B*v2; bb[j]=b00[cB];
    }
    float mx[16], mn[16], sm[16], sq[16];
    #pragma unroll
    for (int s = 0; s < 16; s++) { mx[s]=-1e30f; mn[s]=1e30f; sm[s]=0.f; sq[s]=0.f; }

    for (int it = 0; it < 32; it++) {
        int k = it*64 + wv*16 + l15;
        float r0 = xls[k*3+0]-c0, r1 = xls[k*3+1]-c1, r2 = xls[k*3+2]-c2v;
        half8 bf0, bf1;
        #pragma unroll
        for (int j = 0; j < 8; j++) {
            float pA = fmaf(wa0[j],r0, fmaf(wa1[j],r1, fmaf(wa2[j],r2, ba[j])));
            bf0[j] = (_Float16)fmaxf(pA, 0.f);
            float pB = fmaf(wb0[j],r0, fmaf(wb1[j],r1, fmaf(wb2[j],r2, bb[j])));
            bf1[j] = (_Float16)fmaxf(pB, 0.f);
        }
        #pragma unroll
        for (int t = 0; t < 4; t++) {
            f32x4 acc = {0.f,0.f,0.f,0.f};
            acc = __builtin_amdgcn_mfma_f32_16x16x32_f16(afA[t], bf0, acc, 0, 0, 0);
            acc = __builtin_amdgcn_mfma_f32_16x16x32_f16(afB[t], bf1, acc, 0, 0, 0);
            #pragma unroll
            for (int r = 0; r < 4; r++) {
                float h = acc[r];
                int s = t*4 + r;
                mx[s]=fmaxf(mx[s],h); mn[s]=fminf(mn[s],h);
                sm[s]+=h;             sq[s]=fmaf(h,h,sq[s]);
            }
        }
    }
    #pragma unroll
    for (int m = 1; m < 16; m <<= 1) {
        #pragma unroll
        for (int s = 0; s < 16; s++) {
            mx[s] = fmaxf(mx[s], __shfl_xor(mx[s], m, 64));
            mn[s] = fminf(mn[s], __shfl_xor(mn[s], m, 64));
            sm[s] += __shfl_xor(sm[s], m, 64);
            sq[s] += __shfl_xor(sq[s], m, 64);
        }
    }
    __syncthreads();
    if (l15 == 0) {
        #pragma unroll
        for (int t = 0; t < 4; t++)
            #pragma unroll
            for (int r = 0; r < 4; r++) {
                int o = t*16 + quad*4 + r;
                redM[wv*64+o]=mx[t*4+r]; redN[wv*64+o]=mn[t*4+r];
                redS[wv*64+o]=sm[t*4+r]; redQ[wv*64+o]=sq[t*4+r];
            }
    }
    __syncthreads();
    float Mreg = -1e30f, Nreg = 1e30f;
    if (tid < 64) {
        float S=0.f, Q=0.f;
        #pragma unroll
        for (int w = 0; w < 4; w++) {
            Mreg = fmaxf(Mreg, redM[w*64+tid]); Nreg = fminf(Nreg, redN[w*64+tid]);
            S += redS[w*64+tid];               Q += redQ[w*64+tid];
        }
        atomicAdd(&ws[GBN1 + b_*128 + tid], S);        // chain 15 (per batch)
        atomicAdd(&ws[GBN1 + b_*128 + 64 + tid], Q);
        float sel = (g01[tid] >= 0.f) ? Mreg : Nreg;   // sign(s1)==sign(g01)
        atomicExch(&ws[SELO + bid*64 + tid], sel);
    }

    sbar<1>(wsi, 1, gi, bid, sflag, [&]{         // ---- b1 + BN1 fold ----
        if (tid < 128) {
            float acc = 0.f;
            #pragma unroll
            for (int i = 0; i < 32; i++) acc += aloadf(&ws[GBN1 + i*128 + tid]);
            atomicExch(&ws[FBN1 + tid], acc);
        }
    });

    // local_features out column + s1/t1 (all 480 blocks)
    if (tid < 64) {
        float S = aloadf(&ws[FBN1 + tid]);
        float Q = aloadf(&ws[FBN1 + 64 + tid]);
        float mean = S / N1F;
        float var  = Q / N1F - mean*mean;
        float s1 = g01[tid]*rsqrtf(var + EPS);
        float t1 = b01[tid] - mean*s1;
        float val = fmaxf(fmaf(s1, (s1 >= 0.f) ? Mreg : Nreg, t1), 0.f);
        out[8192 + b_*(67*GG) + (3+tid)*GG + g_] = val;
        s1ls[tid] = s1; t1ls[tid] = t1;
    }

    // ================ tail: all 480 blocks, channel-chunk parallel =============
    // ---- phase A: f2 assembly + h2a rows [base2,base2+nr2) for all 15 pts ----
    if (tid < 45) centb[tid] = aloadf(&ws[CENT + (b_*GG + tid/3)*4 + tid%3]);
    __syncthreads();                   // s1ls/t1ls + centb visible
    if (tid < 15) {
        int s = tid/3, i = tid%3;
        c2b[tid] = (centb[SIDX[s*3+0]*3+i] + centb[SIDX[s*3+1]*3+i]
                  + centb[SIDX[s*3+2]*3+i]) * (1.f/3.f);
    }
    __syncthreads();
    if (tid < 3)
        c3b[tid] = (c2b[tid]+c2b[3+tid]+c2b[6+tid]+c2b[9+tid]+c2b[12+tid]) * 0.2f;
    if (tid < 45) {
        int p = tid/3, i = tid%3;
        f2b[p*69 + i] = centb[SIDX[p]*3+i] - c2b[(p/3)*3 + i];
    }
    for (int u = tid; u < 960; u += 256) {
        int p = u >> 6, ch = u & 63, src = b_*GG + SIDX[p];
        float sel = aloadf(&ws[SELO + src*64 + ch]);
        f2b[p*69 + 3 + ch] = fmaxf(fmaf(s1ls[ch], sel, t1ls[ch]), 0.f);
    }
    __syncthreads();
    if (tid < nr2*15) {
        int rl = tid/15, p = tid%15, r = base2 + rl;
        const float* wr = w10 + r*67;
        const float* fp = &f2b[p*69];
        float h = 0.f;
        #pragma unroll 4
        for (int c = 0; c < 67; c++) h = fmaf(wr[c], fp[c], h);
        atomicExch(&ws[H2A + (b_*GG + p)*128 + r], h);
        hst[rl*15 + p] = h;
    }
    __syncthreads();
    if (tid < nr2) {
        int r = base2 + tid;
        float S = 0.f, Q = 0.f;
        #pragma unroll
        for (int p = 0; p < 15; p++) { float v = hst[tid*15+p]; S += v; Q = fmaf(v,v,Q); }
        atomicAdd(&ws[GS2A + sgrp*256 + r], S);        // chain 16
        atomicAdd(&ws[GS2A + sgrp*256 + 128 + r], Q);
    }
    sbar<1>(wsi, 2, gi, bid, sflag, [&]{         // ---- b2 + BN2a coef fold ----
        if (tid < 128) {
            float S = aloadf(&ws[GS2A + tid])       + aloadf(&ws[GS2A + 256 + tid]);
            float Q = aloadf(&ws[GS2A + 128 + tid]) + aloadf(&ws[GS2A + 256 + 128 + tid]);
            float mean = S / 480.f, var = Q / 480.f - mean*mean;
            float s2 = g10[tid]*rsqrtf(var + EPS);
            atomicExch(&ws[COEF2 + tid], s2);
            atomicExch(&ws[COEF2 + 128 + tid], b10[tid] - mean*s2);
        }
    });

    // ---- phase B: BN2a coefs (2 aloads) + v + h2b rows ----
    if (tid < 128) {
        c2s[tid] = aloadf(&ws[COEF2 + tid]);
        c2t[tid] = aloadf(&ws[COEF2 + 128 + tid]);
    }
    __syncthreads();
    for (int u = tid; u < 1920; u += 256) {
        int p = u >> 7, ch = u & 127;
        float hv = aloadf(&ws[H2A + (b_*GG + p)*128 + ch]);
        vls[p*129 + ch] = fmaxf(fmaf(c2s[ch], hv, c2t[ch]), 0.f);
    }
    __syncthreads();
    if (tid < nr2*15) {
        int rl = tid/15, p = tid%15, r = base2 + rl;
        const float* wr = w11 + r*128;
        const float* vp = &vls[p*129];
        float h = 0.f;
        #pragma unroll 4
        for (int c = 0; c < 128; c++) h = fmaf(wr[c], vp[c], h);
        atomicExch(&ws[H2B + (b_*GG + p)*128 + r], h);
        hst[rl*15 + p] = h;
    }
    __syncthreads();
    if (tid < nr2) {
        int r = base2 + tid;
        float S = 0.f, Q = 0.f;
        #pragma unroll
        for (int p = 0; p < 15; p++) { float v = hst[tid*15+p]; S += v; Q = fmaf(v,v,Q); }
        atomicAdd(&ws[GS2B + sgrp*256 + r], S);
        atomicAdd(&ws[GS2B + sgrp*256 + 128 + r], Q);
    }
    sbar<1>(wsi, 3, gi, bid, sflag, [&]{         // ---- b3 + BN2b coef fold ----
        if (tid < 128) {
            float S = aloadf(&ws[GS2B + tid])       + aloadf(&ws[GS2B + 256 + tid]);
            float Q = aloadf(&ws[GS2B + 128 + tid]) + aloadf(&ws[GS2B + 256 + 128 + tid]);
            float mean = S / 480.f, var = Q / 480.f - mean*mean;
            float s3 = g11[tid]*rsqrtf(var + EPS);
            atomicExch(&ws[COEF3 + tid], s3);
            atomicExch(&ws[COEF3 + 128 + tid], b11[tid] - mean*s3);
        }
    });

    // ---- phase C: BN2b coefs (2 aloads) + lf2/f3 + h3a rows ----
    if (tid < 128) {
        c2s[tid] = aloadf(&ws[COEF3 + tid]);
        c2t[tid] = aloadf(&ws[COEF3 + 128 + tid]);
    }
    __syncthreads();
    for (int u = tid; u < 640; u += 256) {
        int s = u >> 7, ch = u & 127;
        float sv = c2s[ch], tv = c2t[ch], m = -1e30f;
        #pragma unroll
        for (int j = 0; j < 3; j++) {
            float hv = aloadf(&ws[H2B + (b_*GG + 3*s + j)*128 + ch]);
            m = fmaxf(m, fmaxf(fmaf(sv, hv, tv), 0.f));
        }
        f3b[s*132 + 3 + ch] = m;
    }
    if (tid < 15) {
        int s = tid/3, i = tid%3;
        f3b[s*132 + i] = c2b[tid] - c3b[i];
    }
    __syncthreads();
    if (tid < nr3*5) {
        int rl = tid/5, s = tid%5, r = base3 + rl;
        const float* wr = w20 + r*131;
        const float* fp = &f3b[s*132];
        float h = 0.f;
        #pragma unroll 4
        for (int c = 0; c < 131; c++) h = fmaf(wr[c], fp[c], h);
        atomicExch(&ws[H3A + (b_*5 + s)*256 + r], h);
        hst[rl*5 + s] = h;
    }
    __syncthreads();
    if (tid < nr3) {
        int r = base3 + tid;
        float S = 0.f, Q = 0.f;
        #pragma unroll
        for (int s = 0; s < 5; s++) { float v = hst[tid*5+s]; S += v; Q = fmaf(v,v,Q); }
        atomicAdd(&ws[GS3A + sgrp*512 + r], S);
        atomicAdd(&ws[GS3A + sgrp*512 + 256 + r], Q);
    }
    sbar<1>(wsi, 4, gi, bid, sflag, [&]{         // ---- b4 + BN3a coef fold ----
        float S = aloadf(&ws[GS3A + tid])       + aloadf(&ws[GS3A + 512 + tid]);
        float Q = aloadf(&ws[GS3A + 256 + tid]) + aloadf(&ws[GS3A + 512 + 256 + tid]);
        float mean = S / 160.f, var = Q / 160.f - mean*mean;
        float s4 = g20[tid]*rsqrtf(var + EPS);
        atomicExch(&ws[COEF4 + tid], s4);
        atomicExch(&ws[COEF4 + 256 + tid], b20[tid] - mean*s4);
    });

    // ---- phase D: BN3a coefs (2 aloads) + u3 + h3b rows ----
    s4ls[tid] = aloadf(&ws[COEF4 + tid]);
    t4ls[tid] = aloadf(&ws[COEF4 + 256 + tid]);
    __syncthreads();
    for (int u = tid; u < 1280; u += 256) {
        int s = u >> 8, ch = u & 255;
        float hv = aloadf(&ws[H3A + (b_*5 + s)*256 + ch]);
        u3b[s*257 + ch] = fmaxf(fmaf(s4ls[ch], hv, t4ls[ch]), 0.f);
    }
    __syncthreads();
    if (tid < nr3*5) {
        int rl = tid/5, s = tid%5, r = base3 + rl;
        const float* wr = w21 + (size_t)r*256;
        const float* up = &u3b[s*257];
        float h = 0.f;
        #pragma unroll 4
        for (int c = 0; c < 256; c++) h = fmaf(wr[c], up[c], h);
        atomicExch(&ws[H3B + (b_*5 + s)*256 + r], h);
        hst[rl*5 + s] = h;
    }
    __syncthreads();
    if (tid < nr3) {
        int r = base3 + tid;
        float S = 0.f, Q = 0.f;
        #pragma unroll
        for (int s = 0; s < 5; s++) { float v = hst[tid*5+s]; S += v; Q = fmaf(v,v,Q); }
        atomicAdd(&ws[GS3B + sgrp*512 + r], S);
        atomicAdd(&ws[GS3B + sgrp*512 + 256 + r], Q);
    }
    sbar<1>(wsi, 5, gi, bid, sflag, [&]{         // ---- b5 + BN3b coef fold ----
        float S = aloadf(&ws[GS3B + tid])       + aloadf(&ws[GS3B + 512 + tid]);
        float Q = aloadf(&ws[GS3B + 256 + tid]) + aloadf(&ws[GS3B + 512 + 256 + tid]);
        float mean = S / 160.f, var = Q / 160.f - mean*mean;
        float s5 = g21[tid]*rsqrtf(var + EPS);
        atomicExch(&ws[COEF5 + tid], s5);
        atomicExch(&ws[COEF5 + 256 + tid], b21[tid] - mean*s5);
    });

    // ---- phase E: BN3b coefs (2 aloads) + max -> gf (32 blocks write) ----
    if (g_ == 0) {
        float s5 = aloadf(&ws[COEF5 + tid]);
        float t5 = aloadf(&ws[COEF5 + 256 + tid]);
        float m = -1e30f;
        #pragma unroll
        for (int s = 0; s < 5; s++) {
            float hv = aloadf(&ws[H3B + (b_*5 + s)*256 + tid]);
            m = fmaxf(m, fmaxf(fmaf(s5, hv, t5), 0.f));
        }
        out[b_*256 + tid] = m;
    }
}

extern "C" void kernel_launch(void* const* d_in, const int* in_sizes, int n_in,
                              void* d_out, int out_size, void* d_ws, size_t ws_size,
                              hipStream_t stream) {
    (void)in_sizes; (void)n_in; (void)out_size; (void)ws_size;
    const float* x   = (const float*)d_in[0];
    const float* w00 = (const float*)d_in[1];
    const float* g00 = (const float*)d_in[2];
    const float* b00 = (const float*)d_in[3];
    const float* w01 = (const float*)d_in[4];
    const float* g01 = (const float*)d_in[5];
    const float* b01 = (const float*)d_in[6];
    const float* w10 = (const float*)d_in[7];
    const float* g10 = (const float*)d_in[8];
    const float* b10 = (const float*)d_in[9];
    const float* w11 = (const float*)d_in[10];
    const float* g11 = (const float*)d_in[11];
    const float* b11 = (const float*)d_in[12];
    const float* w20 = (const float*)d_in[13];
    const float* g20 = (const float*)d_in[14];
    const float* b20 = (const float*)d_in[15];
    const float* w21 = (const float*)d_in[16];
    const float* g21 = (const float*)d_in[17];
    const float* b21 = (const float*)d_in[18];
    float* out = (float*)d_out;
    float* ws  = (float*)d_ws;

    mega<<<NB, 256, 0, stream>>>(x, w00,g00,b00, w01,g01,b01, w10,g10,b10,
                                 w11,g11,b11, w20,g20,b20, w21,g21,b21, ws, out);
}

// Round 14
// 172.221 us; speedup vs baseline: 1.0773x; 1.0773x over previous
//
#include <hip/hip_runtime.h>
#include <math.h>

#define GG 15
#define KK 2048
#define NB 480               // co-resident: launch_bounds(256,2) -> 512 slots >= 480
#define N1F 983040.0f
#define EPS 1e-5f
#define PZN ((int)0xAAAAAAAA)   // harness poison pattern as int

typedef _Float16 half8 __attribute__((ext_vector_type(8)));
typedef float f32x4 __attribute__((ext_vector_type(4)));

// ---- ws float offsets ----
// R14 = R11 base (sbar depth-1 arrival, conflict-free strides, consumer
// stat reduces -- best-measured pieces; R13's bid0 coef folds REVERTED,
// measured worse) + two serial-chain levers:
//  (1) light-detector swizzle: cg=(g_+14)%15 gives bid0 the SMALL row
//      chunks (nr2=2,nr3=4) so it arrives first and its sweep overlaps
//      other blocks' phase work;
//  (2) in-wait weight prefetch: stage next phase's weight chunk to LDS
//      AFTER the arrival exch, INSIDE the barrier wait (R9 staged BEFORE
//      arrival -> delayed arrival, +8us; this placement costs nobody).
#define CENT  0        // [480][4]   exch: centroid
#define GSREL 1920     // [30][8]    add chain-16: centered moments
#define GBN1  2160     // [32][128]  add chain-15 (per batch): S[64]|Q[64]
#define SELO  6256     // [480][64]  exch: (g01>=0 ? max : min) extremum
#define FBN1  36976    // [128]      exch by bid0 fold of b1
#define H2A   37104    // [480][128] exch: h2a
#define H2B   98544    // [480][128] exch: h2b
#define H3A   159984   // [160][256] exch: h3a
#define H3B   200944   // [160][256] exch: h3b
#define GS2A  241904   // [2][256]   add chain-16: S[128]|Q[128]
#define GS2B  242416   // [2][256]
#define GS3A  242928   // [2][512]   S[256]|Q[256]
#define GS3B  243952   // [2][512] -> 244976
// int offsets (every slot/flag on its own 64B line)
#define CFLG  244976   // [6][30][16]  per-group done flags
#define ARRB  247856   // [6][480][16] per-block arrival slots (exch 1)

#define SMEMF 7936

__device__ const int SIDX[15] = {0,1,8, 2,4,6, 3,5,7, 9,11,13, 10,12,14};

__device__ __forceinline__ float wave_sum(float v){
    for (int off = 32; off; off >>= 1) v += __shfl_down(v, off, 64);
    return v;
}
__device__ __forceinline__ float aloadf(const float* p){
    return __hip_atomic_load(p, __ATOMIC_RELAXED, __HIP_MEMORY_SCOPE_AGENT);
}
__device__ __forceinline__ int aloadi(const int* p){
    return __hip_atomic_load(p, __ATOMIC_RELAXED, __HIP_MEMORY_SCOPE_AGENT);
}
// store-arrival barrier: depth-1 arrival (own slot), bid0 parallel-sweep
// detect + fold + 30 group-flag broadcast; others poll own group flag.
// pref() runs INSIDE the wait (after arrival / after flag set for bid0):
// weight staging overlaps barrier latency instead of the critical path.
template<int SLP, class Fold, class Pref>
__device__ __forceinline__ void sbar(int* wsi, int idx, int gi, int bid,
                                     int* sflag, Fold fold, Pref pref){
    __syncthreads();                    // drains this block's VMEM writes
    if (threadIdx.x == 0)
        atomicExch(&wsi[ARRB + (idx*480 + bid)*16], 1);
    if (bid == 0) {
        int guard = 0, done = 0;
        do {
            int ok = 1;
            for (int s = threadIdx.x; s < 480; s += 256)
                ok &= (aloadi(&wsi[ARRB + (idx*480 + s)*16]) == 1) ? 1 : 0;
            ok = __all(ok) ? 1 : 0;     // 64-lane AND
            if ((threadIdx.x & 63) == 0) sflag[2 + (threadIdx.x >> 6)] = ok;
            __syncthreads();
            done = sflag[2] & sflag[3] & sflag[4] & sflag[5];
            __syncthreads();            // protect sflag reuse next sweep
            if (!done) __builtin_amdgcn_s_sleep(SLP);
        } while (!done && ++guard < 4000000);
        fold();                         // all 480 arrived; data visible
        __syncthreads();                // drain fold exchs (vmcnt 0)
        if (threadIdx.x < 30)
            atomicExch(&wsi[CFLG + (idx*30 + threadIdx.x)*16], 1);
        pref();                         // overlaps pollers' detection
    } else {
        pref();                         // overlaps the barrier wait
    }
    if (threadIdx.x == 0) {
        int g = 0;
        while (aloadi(&wsi[CFLG + (idx*30 + gi)*16]) != 1 && ++g < 8000000)
            __builtin_amdgcn_s_sleep(SLP);
    }
    __syncthreads();
    asm volatile("" ::: "memory");
}
struct NoF { __device__ void operator()() const {} };

__global__ void __launch_bounds__(256, 2) mega(
        const float* __restrict__ x,
        const float* __restrict__ w00, const float* __restrict__ g00, const float* __restrict__ b00,
        const float* __restrict__ w01, const float* __restrict__ g01, const float* __restrict__ b01,
        const float* __restrict__ w10, const float* __restrict__ g10, const float* __restrict__ b10,
        const float* __restrict__ w11, const float* __restrict__ g11, const float* __restrict__ b11,
        const float* __restrict__ w20, const float* __restrict__ g20, const float* __restrict__ b20,
        const float* __restrict__ w21, const float* __restrict__ g21, const float* __restrict__ b21,
        float* __restrict__ ws, float* __restrict__ out) {
    __shared__ __align__(16) float smemf[SMEMF];
    float* xls  = smemf;                       // [6144] phases 1-2 only
    float* redM = smemf + 6144; float* redN = smemf + 6400;
    float* redS = smemf + 6656; float* redQ = smemf + 6912;
    float* bcast= smemf + 7168;
    int*   sflag= (int*)(smemf + 7916);        // [6] ints
    // tail aliases (within xls 0..6143, dead after phase 2) -- conflict-free
    // strides (R9): f2b 69, vls 129, u3b 257. Weight stages:
    //   w10st 6144 [603]  (redM/redN region, front-dead at b1)
    //   wstg  256  (f2b region, dead per-phase: w11st[9][129] b2; w20st
    //              [2358] b3 over dead vls head; w21st[12][257] b4)
    float* s1ls  = smemf;                      // [64]
    float* t1ls  = smemf + 64;                 // [64]
    float* centb = smemf + 128;                // [45]
    float* c2b   = smemf + 176;                // [15]
    float* c3b   = smemf + 192;                // [3]
    float* f2b   = smemf + 256;                // [15][69] -> 1291
    float* wstg  = smemf + 256;                // staged weights (see above)
    float* vls   = smemf + 1424;               // [15][129] -> 3359
    float* f3b   = smemf + 3360;               // [5][132] -> 4020
    float* u3b   = smemf + 4020;               // [5][257] -> 5305
    float* c2s   = smemf + 5312;               // [128]
    float* c2t   = smemf + 5440;               // [128]
    float* s4ls  = smemf + 5568;               // [256]
    float* t4ls  = smemf + 5824;               // [256] -> 6080
    float* w10st = smemf + 6144;               // [603]
    float* hst   = smemf + 6912;               // [135] (redQ region, tail-safe)
    int* wsi = (int*)ws;

    int bid = blockIdx.x, tid = threadIdx.x;
    int b_ = bid / GG, g_ = bid % GG;
    int wv = tid >> 6, lane = tid & 63, l15 = lane & 15, quad = lane >> 4;
    int gi = bid >> 4;                 // 30 groups of 16 (flag polling groups)
    int sgrp = b_ >> 4;                // stats half-group (0/1)
    int cg = (g_ + 14) % 15;           // light-detector swizzle: bid0 -> cg 14
    int base2 = cg*9,  nr2 = (cg == 14) ? 2 : 9;    // L2 row chunk (128 rows)
    int base3 = cg*18, nr3 = (cg == 14) ? 4 : 18;   // L3 row chunk (256 rows)
    int stq = (nr3 < 12) ? nr3 : 12;   // w21 rows staged in LDS

    // ================= phase 1: x -> LDS; centroid + 3x3 moments ===============
    {
        const float4* xp4 = (const float4*)(x + (size_t)bid * KK * 3);
        float4* xls4 = (float4*)xls;
        #pragma unroll
        for (int i = 0; i < 6; i++) xls4[i*256 + tid] = xp4[i*256 + tid];
        __syncthreads();
        float m[9] = {0,0,0,0,0,0,0,0,0};
        float a[24];
        const float* bp = &xls[tid*24];
        #pragma unroll
        for (int i = 0; i < 6; i++)
            *reinterpret_cast<float4*>(&a[i*4]) = *reinterpret_cast<const float4*>(&bp[i*4]);
        #pragma unroll
        for (int p = 0; p < 8; p++) {
            float ax=a[p*3], ay=a[p*3+1], az=a[p*3+2];
            m[0]+=ax; m[1]+=ay; m[2]+=az;
            m[3]=fmaf(ax,ax,m[3]); m[4]=fmaf(ay,ay,m[4]); m[5]=fmaf(az,az,m[5]);
            m[6]=fmaf(ax,ay,m[6]); m[7]=fmaf(ax,az,m[7]); m[8]=fmaf(ay,az,m[8]);
        }
        #pragma unroll
        for (int q = 0; q < 9; q++) {
            float v = wave_sum(m[q]);
            if (lane == 0) redM[q*4 + wv] = v;
        }
        __syncthreads();
        if (tid == 0) {
            float t[9];
            #pragma unroll
            for (int q = 0; q < 9; q++) t[q] = redM[q*4]+redM[q*4+1]+redM[q*4+2]+redM[q*4+3];
            float c0 = t[0]/KK, c1 = t[1]/KK, c2 = t[2]/KK;
            bcast[0]=c0; bcast[1]=c1; bcast[2]=c2;
            out[8192 + b_*(67*GG) + 0*GG + g_] = c0;
            out[8192 + b_*(67*GG) + 1*GG + g_] = c1;
            out[8192 + b_*(67*GG) + 2*GG + g_] = c2;
            atomicExch(&ws[CENT + bid*4 + 0], c0);
            atomicExch(&ws[CENT + bid*4 + 1], c1);
            atomicExch(&ws[CENT + bid*4 + 2], c2);
            redM[40] = t[3] - KK*c0*c0;  redM[41] = t[4] - KK*c1*c1;
            redM[42] = t[5] - KK*c2*c2;  redM[43] = t[6] - KK*c0*c1;
            redM[44] = t[7] - KK*c0*c2;  redM[45] = t[8] - KK*c1*c2;
        }
        __syncthreads();
    }
    if (tid < 6) atomicAdd(&ws[GSREL + gi*8 + tid], redM[40 + tid]);   // chain 16

    // hoisted A-frag prefetch (register dests don't gate the arrival barrier)
    half8 afA[4], afB[4];
    #pragma unroll
    for (int t = 0; t < 4; t++)
        #pragma unroll
        for (int j = 0; j < 8; j++) {
            afA[t][j] = (_Float16)w01[(t*16 + l15)*64 + quad*8 + j];
            afB[t][j] = (_Float16)w01[(t*16 + l15)*64 + 32 + quad*8 + j];
        }

    sbar<1>(wsi, 0, gi, bid, sflag, NoF{}, NoF{});   // ---- b0: moments ready ----

    if (tid < 6) {                               // consumer-side SREL reduce
        float acc = 0.f;
        #pragma unroll
        for (int s = 0; s < 30; s++) acc += aloadf(&ws[GSREL + s*8 + tid]);
        bcast[3+tid] = acc / N1F;
    }
    __syncthreads();
    float c0 = bcast[0], c1 = bcast[1], c2v = bcast[2];
    float S00=bcast[3], S11=bcast[4], S22=bcast[5], S01=bcast[6], S02=bcast[7], S12=bcast[8];

    // ================= phase 2: barrier-free MFMA over 2048 k ==================
    float wa0[8], wa1[8], wa2[8], ba[8], wb0[8], wb1[8], wb2[8], bb[8];
    #pragma unroll
    for (int j = 0; j < 8; j++) {
        int cA = quad*8 + j;
        float u0=w00[cA*3+0], u1=w00[cA*3+1], u2=w00[cA*3+2];
        float var = u0*u0*S00 + u1*u1*S11 + u2*u2*S22
                  + 2.f*(u0*u1*S01 + u0*u2*S02 + u1*u2*S12);
        float a1 = g00[cA]*rsqrtf(var + EPS);
        wa0[j]=a1*u0; wa1[j]=a1*u1; wa2[j]=a1*u2; ba[j]=b00[cA];
        int cB = cA + 32;
        float v0=w00[cB*3+0], v1=w00[cB*3+1], v2=w00[cB*3+2];
        float varB = v0*v0*S00 + v1*v1*S11 + v2*v2*S22
                   + 2.f*(v0*v1*S01 + v0*v2*S02 + v1*v2*S12);
        float a1B = g00[cB]*rsqrtf(varB + EPS);
        wb0[j]=a1B*v0; wb1[j]=a1B*v1; wb2[j]=a1B*v2; bb[j]=b00[cB];
    }
    float mx[16], mn[16], sm[16], sq[16];
    #pragma unroll
    for (int s = 0; s < 16; s++) { mx[s]=-1e30f; mn[s]=1e30f; sm[s]=0.f; sq[s]=0.f; }

    for (int it = 0; it < 32; it++) {
        int k = it*64 + wv*16 + l15;
        float r0 = xls[k*3+0]-c0, r1 = xls[k*3+1]-c1, r2 = xls[k*3+2]-c2v;
        half8 bf0, bf1;
        #pragma unroll
        for (int j = 0; j < 8; j++) {
            float pA = fmaf(wa0[j],r0, fmaf(wa1[j],r1, fmaf(wa2[j],r2, ba[j])));
            bf0[j] = (_Float16)fmaxf(pA, 0.f);
            float pB = fmaf(wb0[j],r0, fmaf(wb1[j],r1, fmaf(wb2[j],r2, bb[j])));
            bf1[j] = (_Float16)fmaxf(pB, 0.f);
        }
        #pragma unroll
        for (int t = 0; t < 4; t++) {
            f32x4 acc = {0.f,0.f,0.f,0.f};
            acc = __builtin_amdgcn_mfma_f32_16x16x32_f16(afA[t], bf0, acc, 0, 0, 0);
            acc = __builtin_amdgcn_mfma_f32_16x16x32_f16(afB[t], bf1, acc, 0, 0, 0);
            #pragma unroll
            for (int r = 0; r < 4; r++) {
                float h = acc[r];
                int s = t*4 + r;
                mx[s]=fmaxf(mx[s],h); mn[s]=fminf(mn[s],h);
                sm[s]+=h;             sq[s]=fmaf(h,h,sq[s]);
            }
        }
    }
    #pragma unroll
    for (int m = 1; m < 16; m <<= 1) {
        #pragma unroll
        for (int s = 0; s < 16; s++) {
            mx[s] = fmaxf(mx[s], __shfl_xor(mx[s], m, 64));
            mn[s] = fminf(mn[s], __shfl_xor(mn[s], m, 64));
            sm[s] += __shfl_xor(sm[s], m, 64);
            sq[s] += __shfl_xor(sq[s], m, 64);
        }
    }
    __syncthreads();
    if (l15 == 0) {
        #pragma unroll
        for (int t = 0; t < 4; t++)
            #pragma unroll
            for (int r = 0; r < 4; r++) {
                int o = t*16 + quad*4 + r;
                redM[wv*64+o]=mx[t*4+r]; redN[wv*64+o]=mn[t*4+r];
                redS[wv*64+o]=sm[t*4+r]; redQ[wv*64+o]=sq[t*4+r];
            }
    }
    __syncthreads();
    float Mreg = -1e30f, Nreg = 1e30f;
    if (tid < 64) {
        float S=0.f, Q=0.f;
        #pragma unroll
        for (int w = 0; w < 4; w++) {
            Mreg = fmaxf(Mreg, redM[w*64+tid]); Nreg = fminf(Nreg, redN[w*64+tid]);
            S += redS[w*64+tid];               Q += redQ[w*64+tid];
        }
        atomicAdd(&ws[GBN1 + b_*128 + tid], S);        // chain 15 (per batch)
        atomicAdd(&ws[GBN1 + b_*128 + 64 + tid], Q);
        float sel = (g01[tid] >= 0.f) ? Mreg : Nreg;   // sign(s1)==sign(g01)
        atomicExch(&ws[SELO + bid*64 + tid], sel);
    }

    sbar<1>(wsi, 1, gi, bid, sflag, [&]{         // ---- b1 + BN1 fold ----
        if (tid < 128) {
            float acc = 0.f;
            #pragma unroll
            for (int i = 0; i < 32; i++) acc += aloadf(&ws[GBN1 + i*128 + tid]);
            atomicExch(&ws[FBN1 + tid], acc);
        }
    }, [&]{                                      // in-wait: stage w10 chunk
        for (int u = tid; u < nr2*67; u += 256) w10st[u] = w10[base2*67 + u];
    });

    // local_features out column + s1/t1 (all 480 blocks)
    if (tid < 64) {
        float S = aloadf(&ws[FBN1 + tid]);
        float Q = aloadf(&ws[FBN1 + 64 + tid]);
        float mean = S / N1F;
        float var  = Q / N1F - mean*mean;
        float s1 = g01[tid]*rsqrtf(var + EPS);
        float t1 = b01[tid] - mean*s1;
        float val = fmaxf(fmaf(s1, (s1 >= 0.f) ? Mreg : Nreg, t1), 0.f);
        out[8192 + b_*(67*GG) + (3+tid)*GG + g_] = val;
        s1ls[tid] = s1; t1ls[tid] = t1;
    }

    // ================ tail: all 480 blocks, channel-chunk parallel =============
    // ---- phase A: f2 assembly + h2a rows [base2,base2+nr2) for all 15 pts ----
    if (tid < 45) centb[tid] = aloadf(&ws[CENT + (b_*GG + tid/3)*4 + tid%3]);
    __syncthreads();                   // s1ls/t1ls + centb visible
    if (tid < 15) {
        int s = tid/3, i = tid%3;
        c2b[tid] = (centb[SIDX[s*3+0]*3+i] + centb[SIDX[s*3+1]*3+i]
                  + centb[SIDX[s*3+2]*3+i]) * (1.f/3.f);
    }
    __syncthreads();
    if (tid < 3)
        c3b[tid] = (c2b[tid]+c2b[3+tid]+c2b[6+tid]+c2b[9+tid]+c2b[12+tid]) * 0.2f;
    if (tid < 45) {
        int p = tid/3, i = tid%3;
        f2b[p*69 + i] = centb[SIDX[p]*3+i] - c2b[(p/3)*3 + i];
    }
    for (int u = tid; u < 960; u += 256) {
        int p = u >> 6, ch = u & 63, src = b_*GG + SIDX[p];
        float sel = aloadf(&ws[SELO + src*64 + ch]);
        f2b[p*69 + 3 + ch] = fmaxf(fmaf(s1ls[ch], sel, t1ls[ch]), 0.f);
    }
    __syncthreads();
    if (tid < nr2*15) {
        int rl = tid/15, p = tid%15, r = base2 + rl;
        const float* wr = &w10st[rl*67];
        const float* fp = &f2b[p*69];
        float h = 0.f;
        #pragma unroll 4
        for (int c = 0; c < 67; c++) h = fmaf(wr[c], fp[c], h);
        atomicExch(&ws[H2A + (b_*GG + p)*128 + r], h);
        hst[rl*15 + p] = h;
    }
    __syncthreads();
    if (tid < nr2) {
        int r = base2 + tid;
        float S = 0.f, Q = 0.f;
        #pragma unroll
        for (int p = 0; p < 15; p++) { float v = hst[tid*15+p]; S += v; Q = fmaf(v,v,Q); }
        atomicAdd(&ws[GS2A + sgrp*256 + r], S);        // chain 16
        atomicAdd(&ws[GS2A + sgrp*256 + 128 + r], Q);
    }
    sbar<1>(wsi, 2, gi, bid, sflag, NoF{}, [&]{  // ---- b2 + stage w11 chunk ----
        for (int u = tid; u < nr2*128; u += 256)
            wstg[(u>>7)*129 + (u&127)] = w11[base2*128 + u];
    });

    // ---- phase B: BN2a coefs + v + h2b rows ----
    if (tid < 128) {
        float S = aloadf(&ws[GS2A + tid])       + aloadf(&ws[GS2A + 256 + tid]);
        float Q = aloadf(&ws[GS2A + 128 + tid]) + aloadf(&ws[GS2A + 256 + 128 + tid]);
        float mean = S / 480.f, var = Q / 480.f - mean*mean;
        float s2 = g10[tid]*rsqrtf(var + EPS);
        c2s[tid] = s2; c2t[tid] = b10[tid] - mean*s2;
    }
    __syncthreads();
    for (int u = tid; u < 1920; u += 256) {
        int p = u >> 7, ch = u & 127;
        float hv = aloadf(&ws[H2A + (b_*GG + p)*128 + ch]);
        vls[p*129 + ch] = fmaxf(fmaf(c2s[ch], hv, c2t[ch]), 0.f);
    }
    __syncthreads();
    if (tid < nr2*15) {
        int rl = tid/15, p = tid%15, r = base2 + rl;
        const float* wr = &wstg[rl*129];
        const float* vp = &vls[p*129];
        float h = 0.f;
        #pragma unroll 4
        for (int c = 0; c < 128; c++) h = fmaf(wr[c], vp[c], h);
        atomicExch(&ws[H2B + (b_*GG + p)*128 + r], h);
        hst[rl*15 + p] = h;
    }
    __syncthreads();
    if (tid < nr2) {
        int r = base2 + tid;
        float S = 0.f, Q = 0.f;
        #pragma unroll
        for (int p = 0; p < 15; p++) { float v = hst[tid*15+p]; S += v; Q = fmaf(v,v,Q); }
        atomicAdd(&ws[GS2B + sgrp*256 + r], S);
        atomicAdd(&ws[GS2B + sgrp*256 + 128 + r], Q);
    }
    sbar<1>(wsi, 3, gi, bid, sflag, NoF{}, [&]{  // ---- b3 + stage w20 chunk ----
        for (int u = tid; u < nr3*131; u += 256) wstg[u] = w20[base3*131 + u];
    });

    // ---- phase C: BN2b coefs + lf2/f3 + h3a rows ----
    if (tid < 128) {
        float S = aloadf(&ws[GS2B + tid])       + aloadf(&ws[GS2B + 256 + tid]);
        float Q = aloadf(&ws[GS2B + 128 + tid]) + aloadf(&ws[GS2B + 256 + 128 + tid]);
        float mean = S / 480.f, var = Q / 480.f - mean*mean;
        float s3 = g11[tid]*rsqrtf(var + EPS);
        c2s[tid] = s3; c2t[tid] = b11[tid] - mean*s3;
    }
    __syncthreads();
    for (int u = tid; u < 640; u += 256) {
        int s = u >> 7, ch = u & 127;
        float sv = c2s[ch], tv = c2t[ch], m = -1e30f;
        #pragma unroll
        for (int j = 0; j < 3; j++) {
            float hv = aloadf(&ws[H2B + (b_*GG + 3*s + j)*128 + ch]);
            m = fmaxf(m, fmaxf(fmaf(sv, hv, tv), 0.f));
        }
        f3b[s*132 + 3 + ch] = m;
    }
    if (tid < 15) {
        int s = tid/3, i = tid%3;
        f3b[s*132 + i] = c2b[tid] - c3b[i];
    }
    __syncthreads();
    if (tid < nr3*5) {
        int rl = tid/5, s = tid%5, r = base3 + rl;
        const float* wr = &wstg[rl*131];
        const float* fp = &f3b[s*132];
        float h = 0.f;
        #pragma unroll 4
        for (int c = 0; c < 131; c++) h = fmaf(wr[c], fp[c], h);
        atomicExch(&ws[H3A + (b_*5 + s)*256 + r], h);
        hst[rl*5 + s] = h;
    }
    __syncthreads();
    if (tid < nr3) {
        int r = base3 + tid;
        float S = 0.f, Q = 0.f;
        #pragma unroll
        for (int s = 0; s < 5; s++) { float v = hst[tid*5+s]; S += v; Q = fmaf(v,v,Q); }
        atomicAdd(&ws[GS3A + sgrp*512 + r], S);
        atomicAdd(&ws[GS3A + sgrp*512 + 256 + r], Q);
    }
    sbar<1>(wsi, 4, gi, bid, sflag, NoF{}, [&]{  // ---- b4 + stage w21 rows ----
        for (int u = tid; u < stq*256; u += 256)
            wstg[(u>>8)*257 + (u&255)] = w21[base3*256 + u];
    });

    // ---- phase D: BN3a coefs + u3 + h3b rows ----
    {
        float S = aloadf(&ws[GS3A + tid])       + aloadf(&ws[GS3A + 512 + tid]);
        float Q = aloadf(&ws[GS3A + 256 + tid]) + aloadf(&ws[GS3A + 512 + 256 + tid]);
        float mean = S / 160.f, var = Q / 160.f - mean*mean;
        float s4 = g20[tid]*rsqrtf(var + EPS);
        s4ls[tid] = s4; t4ls[tid] = b20[tid] - mean*s4;
    }
    __syncthreads();
    for (int u = tid; u < 1280; u += 256) {
        int s = u >> 8, ch = u & 255;
        float hv = aloadf(&ws[H3A + (b_*5 + s)*256 + ch]);
        u3b[s*257 + ch] = fmaxf(fmaf(s4ls[ch], hv, t4ls[ch]), 0.f);
    }
    __syncthreads();
    if (tid < nr3*5) {
        int rl = tid/5, s = tid%5, r = base3 + rl;
        const float* up = &u3b[s*257];
        float h = 0.f;
        if (rl < 12) {
            const float* wr = &wstg[rl*257];
            #pragma unroll 4
            for (int c = 0; c < 256; c++) h = fmaf(wr[c], up[c], h);
        } else {
            const float* wr = w21 + (size_t)r*256;
            #pragma unroll 4
            for (int c = 0; c < 256; c++) h = fmaf(wr[c], up[c], h);
        }
        atomicExch(&ws[H3B + (b_*5 + s)*256 + r], h);
        hst[rl*5 + s] = h;
    }
    __syncthreads();
    if (tid < nr3) {
        int r = base3 + tid;
        float S = 0.f, Q = 0.f;
        #pragma unroll
        for (int s = 0; s < 5; s++) { float v = hst[tid*5+s]; S += v; Q = fmaf(v,v,Q); }
        atomicAdd(&ws[GS3B + sgrp*512 + r], S);
        atomicAdd(&ws[GS3B + sgrp*512 + 256 + r], Q);
    }
    sbar<1>(wsi, 5, gi, bid, sflag, NoF{}, NoF{});   // ---- b5: S3B ready ----

    // ---- phase E: BN3b + max -> gf (32 blocks write) ----
    if (g_ == 0) {
        float S = aloadf(&ws[GS3B + tid])       + aloadf(&ws[GS3B + 512 + tid]);
        float Q = aloadf(&ws[GS3B + 256 + tid]) + aloadf(&ws[GS3B + 512 + 256 + tid]);
        float mean = S / 160.f, var = Q / 160.f - mean*mean;
        float s5 = g21[tid]*rsqrtf(var + EPS);
        float t5 = b21[tid] - mean*s5;
        float m = -1e30f;
        #pragma unroll
        for (int s = 0; s < 5; s++) {
            float hv = aloadf(&ws[H3B + (b_*5 + s)*256 + tid]);
            m = fmaxf(m, fmaxf(fmaf(s5, hv, t5), 0.f));
        }
        out[b_*256 + tid] = m;
    }
}

extern "C" void kernel_launch(void* const* d_in, const int* in_sizes, int n_in,
                              void* d_out, int out_size, void* d_ws, size_t ws_size,
                              hipStream_t stream) {
    (void)in_sizes; (void)n_in; (void)out_size; (void)ws_size;
    const float* x   = (const float*)d_in[0];
    const float* w00 = (const float*)d_in[1];
    const float* g00 = (const float*)d_in[2];
    const float* b00 = (const float*)d_in[3];
    const float* w01 = (const float*)d_in[4];
    const float* g01 = (const float*)d_in[5];
    const float* b01 = (const float*)d_in[6];
    const float* w10 = (const float*)d_in[7];
    const float* g10 = (const float*)d_in[8];
    const float* b10 = (const float*)d_in[9];
    const float* w11 = (const float*)d_in[10];
    const float* g11 = (const float*)d_in[11];
    const float* b11 = (const float*)d_in[12];
    const float* w20 = (const float*)d_in[13];
    const float* g20 = (const float*)d_in[14];
    const float* b20 = (const float*)d_in[15];
    const float* w21 = (const float*)d_in[16];
    const float* g21 = (const float*)d_in[17];
    const float* b21 = (const float*)d_in[18];
    float* out = (float*)d_out;
    float* ws  = (float*)d_ws;

    mega<<<NB, 256, 0, stream>>>(x, w00,g00,b00, w01,g01,b01, w10,g10,b10,
                                 w11,g11,b11, w20,g20,b20, w21,g21,b21, ws, out);
}